// Round 8
// baseline (1550.268 us; speedup 1.0000x reference)
//
#include <hip/hip_runtime.h>
#include <math.h>
#include <stdint.h>

#define NBATCH 2048

struct Args {
    const float* x;
    const float* W[7];
    const float* G[7];
    const float* Bt[7];
    const float* WFC;
    float* out;
    float* bufA;        // ws+0, 29,425,664 B
    float* bufB;        // ws+29,425,664, 13,631,488 B
    double* slotD1;     // L1 stats: bufB+0, 64 slots x 16 doubles
    long long* slotB2;  // L2 stats: bufB+12,582,912, 256 x 24 int64
    long long* holeA;   // L3..L7 stats: bufA+20,971,520, 9216 int64 (73,728 B)
    float2* ab;         // ws+43,057,152: 8 layers x 128 float2
    float* wsc;         // ws+43,065,344: 321 floats
    int* cnt;           // ws+43,066,688: 16 ints
    uint32_t* wmb;      // d_out scratch, dead until fc writes
};

__device__ __forceinline__ float signf(float v) {
    return (v > 0.f) ? 1.f : ((v < 0.f) ? -1.f : 0.f);
}

// ---------------- setup: zero slots/counters, weight scales, bit-pack -------
__global__ __launch_bounds__(256) void k_setup(Args a) {
    const int blk = blockIdx.x, tid = threadIdx.x;
    const int gtid = blk * 256 + tid, stride = 391 * 256;
    for (int i = gtid; i < 1024; i += stride) a.slotD1[i] = 0.0;
    for (int i = gtid; i < 6144; i += stride) a.slotB2[i] = 0;
    if (gtid < 16) a.cnt[gtid] = 0;

    if (blk < 321 && tid < 64) {   // mean|w| per output channel
        const int cum[9] = {0,8,20,52,116,180,244,316,321};
        const int per[8] = {16,96,108,224,320,192,192,216};
        const float* wsrc[8] = {a.W[0],a.W[1],a.W[2],a.W[3],a.W[4],a.W[5],a.W[6],a.WFC};
        int o = blk, L = 0;
        while (L < 7 && o >= cum[L + 1]) ++L;
        const int oo = o - cum[L], p = per[L];
        const float* wo = wsrc[L] + (size_t)oo * p;
        float s = 0.f;
        for (int i = tid; i < p; i += 64) s += fabsf(wo[i]);
        #pragma unroll
        for (int off = 32; off; off >>= 1) s += __shfl_down(s, off);
        if (tid == 0) a.wsc[o] = s / (float)p;
    }

    const int gid = (blk - 384) * 256 + tid;   // blocks 384..390: pack signs
    if (blk >= 384 && gid >= 0 && gid < 1608) {
        const int cum[7]  = {0,144,432,880,1200,1392,1608};
        const int cin[6]  = {8,12,32,64,64,64};
        const int kk[6]   = {12,9,7,5,3,3};
        const int wpp[6]  = {1,1,1,2,2,2};
        const int woff[6] = {0,144,432,880,1520,1904};
        const float* wsrc[6] = {a.W[1],a.W[2],a.W[3],a.W[4],a.W[5],a.W[6]};
        int L = 0;
        while (L < 5 && gid >= cum[L + 1]) ++L;
        const int idx = gid - cum[L];
        const int K = kk[L], CIN = cin[L], WPP = wpp[L];
        const int o = idx / K, k = idx - o * K;
        const float* w = wsrc[L];
        uint32_t m0 = 0, m1 = 0;
        for (int c = 0; c < CIN; ++c) {
            const float v = w[((size_t)o * CIN + c) * K + k];
            const uint32_t bit = (v < 0.f) ? 1u : 0u;
            if (c < 32) m0 |= bit << c; else m1 |= bit << (c - 32);
        }
        uint32_t* dst = a.wmb + woff[L] + (size_t)idx * WPP;
        dst[0] = m0;
        if (WPP == 2) dst[1] = m1;
    }
}

// ---------------- layer 1: register conv + last-block BN fold ---------------
__global__ __launch_bounds__(256) void k_conv1(Args a) {
    __shared__ float wgs[128];
    __shared__ double sred[16];
    __shared__ int lastF;
    const int n = blockIdx.x, tid = threadIdx.x, l = tid & 63;
    if (tid < 128) wgs[tid] = signf(a.W[0][tid]);
    if (tid < 16)  sred[tid] = 0.0;
    __syncthreads();
    const int r = tid;
    const float* xn = a.x + (size_t)n * 3600;
    float m0[8], m1[8];
    #pragma unroll
    for (int ch = 0; ch < 8; ++ch) { m0[ch] = 0.f; m1[ch] = 0.f; }
    if (r < 225) {
        float f[40];   // f[i] = x[16r-8+i]; taps f[2j+1+k] for p=8r+j
        const int g0 = 16 * r - 8;
        #pragma unroll
        for (int b = 0; b < 10; ++b) {
            const int gg = g0 + 4 * b;
            if (gg >= 0 && gg <= 3596) {
                const float4 v = *(const float4*)(xn + gg);
                f[4*b] = v.x; f[4*b+1] = v.y; f[4*b+2] = v.z; f[4*b+3] = v.w;
            } else {
                f[4*b] = 0.f; f[4*b+1] = 0.f; f[4*b+2] = 0.f; f[4*b+3] = 0.f;
            }
        }
        #pragma unroll
        for (int ch = 0; ch < 8; ++ch) {
            float acc[12];
            #pragma unroll
            for (int j = 0; j < 12; ++j) acc[j] = 0.f;
            #pragma unroll
            for (int k = 0; k < 16; ++k) {
                const float wk = wgs[ch * 16 + k];
                #pragma unroll
                for (int j = 0; j < 12; ++j)
                    acc[j] = fmaf(f[2*j + 1 + k], wk, acc[j]);
            }
            const float lo  = fmaxf(fmaxf(acc[0], acc[1]), fmaxf(acc[2], acc[3]));
            const float mid = fmaxf(fmaxf(acc[4], acc[5]), fmaxf(acc[6], acc[7]));
            const float hi  = fmaxf(fmaxf(acc[8], acc[9]), fmaxf(acc[10], acc[11]));
            const float sc = a.wsc[ch];
            m0[ch] = fmaxf(lo, mid) * sc;
            m1[ch] = (r < 224) ? fmaxf(mid, hi) * sc : 0.f;
        }
        float* on = a.bufA + ((size_t)n * 449 + 2 * r) * 8;
        *(float4*)(on + 0) = make_float4(m0[0], m0[1], m0[2], m0[3]);
        *(float4*)(on + 4) = make_float4(m0[4], m0[5], m0[6], m0[7]);
        if (r < 224) {
            *(float4*)(on + 8)  = make_float4(m1[0], m1[1], m1[2], m1[3]);
            *(float4*)(on + 12) = make_float4(m1[4], m1[5], m1[6], m1[7]);
        }
    }
    #pragma unroll
    for (int ch = 0; ch < 8; ++ch) {
        double sS = (double)m0[ch] + (double)m1[ch];
        double s2 = (double)m0[ch] * m0[ch] + (double)m1[ch] * m1[ch];
        #pragma unroll
        for (int off = 32; off; off >>= 1) {
            sS += __shfl_down(sS, off);
            s2 += __shfl_down(s2, off);
        }
        if (l == 0) {
            atomicAdd(&sred[ch], sS);
            atomicAdd(&sred[8 + ch], s2);
        }
    }
    __syncthreads();
    if (tid < 16) {
        double* so = a.slotD1 + (size_t)(n & 63) * 16;
        atomicAdd(&so[tid], sred[tid]);
    }
    // ---- last-block fold: L1 BN affine -> ab[0..7] ----
    __threadfence();
    __syncthreads();
    if (tid == 0) lastF = (atomicAdd(a.cnt, 1) == NBATCH - 1) ? 1 : 0;
    __syncthreads();
    if (lastF) {
        __threadfence();
        volatile const double* vs = a.slotD1;
        if (tid < 16) {
            double s = 0.0;
            #pragma unroll 8
            for (int sl = 0; sl < 64; ++sl) s += vs[sl * 16 + tid];
            sred[tid] = s;
        }
        __syncthreads();
        if (tid < 8) {
            const double cInv = 1.0 / 919552.0;
            const double mean = sred[tid] * cInv;
            const double var  = sred[8 + tid] * cInv - mean * mean;
            const double A = (double)a.G[0][tid] / sqrt(var + 1e-5);
            const double B = (double)a.Bt[0][tid] - mean * A;
            a.ab[tid] = make_float2((float)A, (float)B);
        }
    }
}

// ---------------- layers 2..7: wave-per-(sample, lp-slice) binary conv ------
// Int64 stats atomics into slots; last block folds slots -> abOut and zeroes
// the holeA scratch for the next layer.
template <int CIN, int LIN, int O, int K, int STRIDE, int PAD,
          int PK, int PS, int LP, int WPP, int LPB, int SPLIT, int SLOTSN>
__global__ __launch_bounds__(64) void k_bin(
    const float* __restrict__ xprev, const uint32_t* __restrict__ wm,
    const float* __restrict__ wsc, const float2* __restrict__ abIn,
    const float* __restrict__ gammaL, const float* __restrict__ betaL,
    float* __restrict__ out, long long* __restrict__ slots,
    float2* __restrict__ abOut, long long* __restrict__ zro,
    int* __restrict__ cnt)
{
    constexpr int OL    = (O < 64) ? O : 64;
    constexpr int PO    = 64 / OL;
    constexpr int SPAN  = (PK - 1) * STRIDE + K;
    constexpr int SHIFT = (WPP == 1) ? (PAD & 1) : 0;
    constexpr int XMN   = LPB * PS * STRIDE + SPAN + 2;
    constexpr int XM64N = (WPP == 2) ? XMN : ((XMN + 2) / 2 + 1);

    __shared__ uint64_t xmbuf[XM64N];
    __shared__ long long sums[192];
    uint32_t* xm32 = (uint32_t*)xmbuf;
    uint64_t* xm64 = xmbuf;

    const int n = blockIdx.x, sp = blockIdx.y, l = threadIdx.x;
    const int lp0 = sp * LPB;
    const int lp1 = (lp0 + LPB < LP) ? lp0 + LPB : LP;
    const int q0raw = lp0 * PS * STRIDE - PAD;
    const int q0 = (q0raw > 0) ? q0raw : 0;
    const int q1raw = (lp1 - 1) * PS * STRIDE - PAD + SPAN;
    const int q1 = (q1raw < LIN) ? q1raw : LIN;
    const int S0 = (WPP == 1) ? ((q0 + SHIFT) & 1) : 0;
    const int xbase = q0 - S0;

    const float* xn = xprev + (size_t)n * LIN * CIN;

    float aA = 0.f, aB = 0.f;
    if (l < CIN) { const float2 t = abIn[l]; aA = t.x; aB = t.y; }

    // ---- pack slice [q0, q1) ----
    if constexpr (CIN == 64) {
        #pragma unroll 4
        for (int pos = q0; pos < q1; ++pos) {
            const float v = fmaf(aA, xn[pos * 64 + l], aB);
            const unsigned long long bal = __ballot(v < 0.f);
            if (l == 0) xm64[pos - xbase] = (uint64_t)bal;
        }
    } else {
        constexpr int PPW = 64 / CIN;
        const int pw = l / CIN, c = l - pw * CIN;
        const float myA = __shfl(aA, c), myB = __shfl(aB, c);
        const bool lact = (pw < PPW);
        for (int pb = q0; pb < q1; pb += PPW) {
            const int pos = pb + pw;
            const bool act = lact && (pos < q1);
            float v = 0.f;
            if (act) v = fmaf(myA, xn[(size_t)pb * CIN + l], myB);
            const unsigned long long bal = __ballot(act && (v < 0.f));
            if (act && c == 0) {
                uint32_t mk;
                if constexpr (CIN == 32) mk = (uint32_t)(bal >> (pw * 32));
                else mk = (uint32_t)(bal >> (pw * CIN)) & (uint32_t)((1u << CIN) - 1);
                xm32[pos - xbase] = mk;
            }
        }
    }
    __syncthreads();

    // ---- conv + pool + int stats over [lp0, lp1) ----
    const int po = l / OL, oo = l - po * OL;
    const bool cact = (po < PO);
    const float myws = cact ? wsc[oo] : 0.f;
    float* on = out + (size_t)n * LP * O;
    int accS = 0, accS2 = 0;
    long long* so = slots + (size_t)((n * SPLIT + sp) & (SLOTSN - 1)) * (2 * O);

    if constexpr (WPP == 2) {
        const uint64_t* wmp = (const uint64_t*)wm;
        uint64_t wr[K];
        #pragma unroll
        for (int k = 0; k < K; ++k) wr[k] = wmp[oo * K + k];
        uint64_t wr2[K];
        const int oo2 = 64 + ((O > 64 && l < O - 64) ? l : 0);
        if constexpr (O > 64) {
            #pragma unroll
            for (int k = 0; k < K; ++k) wr2[k] = wmp[oo2 * K + k];
        }
        const float myws2 = (O > 64 && l < O - 64) ? wsc[64 + l] : 0.f;
        int accSb = 0, accS2b = 0;

        for (int lp = lp0 + po; lp < lp1; lp += PO) {
            const int lo = lp * PS * STRIDE - PAD;
            int m = -1000000, m2 = -1000000;
            if (lo >= 0 && lo + SPAN <= LIN) {
                uint64_t tw[SPAN];
                #pragma unroll
                for (int t = 0; t < SPAN; ++t) tw[t] = xm64[lo - xbase + t];
                #pragma unroll
                for (int j = 0; j < PK; ++j) {
                    int p = 0;
                    #pragma unroll
                    for (int k = 0; k < K; ++k)
                        p += __popcll(tw[j * STRIDE + k] ^ wr[k]);
                    m = max(m, CIN * K - 2 * p);
                    if constexpr (O > 64) {
                        int p2 = 0;
                        #pragma unroll
                        for (int k = 0; k < K; ++k)
                            p2 += __popcll(tw[j * STRIDE + k] ^ wr2[k]);
                        m2 = max(m2, CIN * K - 2 * p2);
                    }
                }
            } else {
                #pragma unroll
                for (int j = 0; j < PK; ++j) {
                    const int base = lo + j * STRIDE;
                    int p = 0, nv = 0, p2 = 0;
                    #pragma unroll
                    for (int k = 0; k < K; ++k) {
                        const int q = base + k;
                        if (q >= 0 && q < LIN) {
                            ++nv;
                            const uint64_t xv = xm64[q - xbase];
                            p += __popcll(xv ^ wr[k]);
                            if constexpr (O > 64) p2 += __popcll(xv ^ wr2[k]);
                        }
                    }
                    m = max(m, CIN * nv - 2 * p);
                    if constexpr (O > 64) m2 = max(m2, CIN * nv - 2 * p2);
                }
            }
            on[lp * O + oo] = (float)m * myws;
            accS += m; accS2 += m * m;
            if constexpr (O > 64) {
                if (l < O - 64) on[lp * O + 64 + l] = (float)m2 * myws2;
                accSb += m2; accS2b += m2 * m2;
            }
        }
        atomicAdd((unsigned long long*)&so[oo], (unsigned long long)(long long)accS);
        atomicAdd((unsigned long long*)&so[O + oo], (unsigned long long)(long long)accS2);
        if constexpr (O > 64) {
            if (l < O - 64) {
                atomicAdd((unsigned long long*)&so[64 + l], (unsigned long long)(long long)accSb);
                atomicAdd((unsigned long long*)&so[O + 64 + l], (unsigned long long)(long long)accS2b);
            }
        }
    } else {
        uint32_t wr[K];
        #pragma unroll
        for (int k = 0; k < K; ++k) wr[k] = wm[oo * K + k];

        constexpr int PAIRS = (SPAN + 1) / 2;
        for (int lp = lp0 + po; lp < lp1; lp += PO) {
            const int lo = lp * PS * STRIDE - PAD;
            int m = -1000000;
            if (lo >= 0 && lo + SPAN <= LIN) {
                uint32_t tw[PAIRS * 2];
                const int e0 = (lo - xbase) >> 1;
                #pragma unroll
                for (int i = 0; i < PAIRS; ++i) {
                    const uint64_t u = xmbuf[e0 + i];
                    tw[2 * i]     = (uint32_t)u;
                    tw[2 * i + 1] = (uint32_t)(u >> 32);
                }
                #pragma unroll
                for (int j = 0; j < PK; ++j) {
                    int p = 0;
                    #pragma unroll
                    for (int k = 0; k < K; ++k)
                        p += __popc(tw[j * STRIDE + k] ^ wr[k]);
                    m = max(m, CIN * K - 2 * p);
                }
            } else {
                #pragma unroll
                for (int j = 0; j < PK; ++j) {
                    const int base = lo + j * STRIDE;
                    int p = 0, nv = 0;
                    #pragma unroll
                    for (int k = 0; k < K; ++k) {
                        const int q = base + k;
                        if (q >= 0 && q < LIN) { ++nv; p += __popc(xm32[q - xbase] ^ wr[k]); }
                    }
                    m = max(m, CIN * nv - 2 * p);
                }
            }
            if (cact) {
                on[lp * O + oo] = (float)m * myws;
                accS += m; accS2 += m * m;
            }
        }
        if constexpr (PO > 1) {
            int t = accS, t2 = accS2;
            #pragma unroll
            for (int g = 1; g < PO; ++g) {
                t  += __shfl(accS,  l + g * OL);
                t2 += __shfl(accS2, l + g * OL);
            }
            if (l < OL) {
                atomicAdd((unsigned long long*)&so[l], (unsigned long long)(long long)t);
                atomicAdd((unsigned long long*)&so[O + l], (unsigned long long)(long long)t2);
            }
        } else {
            atomicAdd((unsigned long long*)&so[oo], (unsigned long long)(long long)accS);
            atomicAdd((unsigned long long*)&so[O + oo], (unsigned long long)(long long)accS2);
        }
    }

    // ---- last-block: fold slots -> abOut, zero holeA for next layer ----
    __threadfence();
    int p = 0;
    if (l == 0) p = atomicAdd(cnt, 1);
    p = __shfl(p, 0);
    if (p == NBATCH * SPLIT - 1) {
        __threadfence();
        constexpr int A2 = 2 * O;
        long long s0 = 0, s1 = 0, s2 = 0;
        volatile const long long* vs = slots;
        #pragma unroll 4
        for (int sl = 0; sl < SLOTSN; ++sl) {
            const int b = sl * A2;
            if (l < A2) s0 += vs[b + l];
            if constexpr (A2 > 64) { if (l + 64 < A2) s1 += vs[b + l + 64]; }
            if constexpr (A2 > 128) { if (l + 128 < A2) s2 += vs[b + l + 128]; }
        }
        if (l < A2) sums[l] = s0;
        if constexpr (A2 > 64) { if (l + 64 < A2) sums[l + 64] = s1; }
        if constexpr (A2 > 128) { if (l + 128 < A2) sums[l + 128] = s2; }
        __syncthreads();
        constexpr double cInv = 1.0 / ((double)NBATCH * (double)LP);
        #pragma unroll
        for (int g = 0; g < (O + 63) / 64; ++g) {
            const int c = l + g * 64;
            if (c < O) {
                const double w  = (double)wsc[c];
                const double Sx  = w * (double)sums[c];
                const double Sx2 = w * w * (double)sums[O + c];
                const double mean = Sx * cInv;
                const double var  = Sx2 * cInv - mean * mean;
                const double A = (double)gammaL[c] / sqrt(var + 1e-5);
                const double B = (double)betaL[c] - mean * A;
                abOut[c] = make_float2((float)A, (float)B);
            }
        }
        for (int i = l; i < 9216; i += 64) zro[i] = 0;
    }
}

// ---------------- FC, wave-per-sample (reads folded ab7) --------------------
__global__ __launch_bounds__(64) void k_fc(Args a) {
    const int n = blockIdx.x, l = threadIdx.x;
    const float2* ab7 = a.ab + 768;
    const float2 t0 = ab7[l];
    const float aA0 = t0.x, aB0 = t0.y;
    float aA1 = 0.f, aB1 = 0.f;
    if (l < 8) { const float2 t1 = ab7[64 + l]; aA1 = t1.x; aB1 = t1.y; }

    const float* p7 = a.bufA + (size_t)n * 216;
    float acc[5] = {0.f, 0.f, 0.f, 0.f, 0.f};
    #pragma unroll
    for (int j = 0; j < 4; ++j) {
        const int i = l + 64 * j;
        const int ic = (i < 216) ? i : 215;
        const int c = ic / 3, lp = ic - 3 * c;       // flatten is [72,3]
        float aa = __shfl(aA0, c);
        float bb = __shfl(aB0, c);
        const float aaH = __shfl(aA1, c - 64);
        const float bbH = __shfl(aB1, c - 64);
        if (c >= 64) { aa = aaH; bb = bbH; }
        if (i < 216) {
            const float av = signf(fmaf(aa, p7[lp * 72 + c], bb));
            #pragma unroll
            for (int o = 0; o < 5; ++o)
                acc[o] += av * signf(a.WFC[o * 216 + i]);
        }
    }
    #pragma unroll
    for (int o = 0; o < 5; ++o) {
        float v = acc[o];
        #pragma unroll
        for (int off = 32; off; off >>= 1) v += __shfl_down(v, off);
        if (l == 0) a.out[(size_t)n * 5 + o] = v * a.wsc[316 + o];
    }
}

extern "C" void kernel_launch(void* const* d_in, const int* in_sizes, int n_in,
                              void* d_out, int out_size, void* d_ws, size_t ws_size,
                              hipStream_t stream) {
    Args a;
    a.x = (const float*)d_in[0];
    for (int i = 0; i < 7; ++i) {
        a.W[i]  = (const float*)d_in[1 + 3 * i];
        a.G[i]  = (const float*)d_in[2 + 3 * i];
        a.Bt[i] = (const float*)d_in[3 + 3 * i];
    }
    a.WFC = (const float*)d_in[22];
    a.out = (float*)d_out;

    char* ws = (char*)d_ws;
    a.bufA   = (float*)ws;
    a.bufB   = (float*)(ws + 29425664);
    a.slotD1 = (double*)(ws + 29425664);              // bufB hole (dead in conv1)
    a.slotB2 = (long long*)(ws + 29425664 + 12582912);// bufB tail hole
    a.holeA  = (long long*)(ws + 20971520);           // bufA tail hole
    a.ab     = (float2*)(ws + 43057152);
    a.wsc    = (float*)(ws + 43065344);
    a.cnt    = (int*)(ws + 43066688);
    a.wmb    = (uint32_t*)d_out;

    float2* ab1 = a.ab + 0,   *ab2 = a.ab + 128, *ab3 = a.ab + 256;
    float2* ab4 = a.ab + 384, *ab5 = a.ab + 512, *ab6 = a.ab + 640;
    float2* ab7 = a.ab + 768;

    k_setup<<<391, 256, 0, stream>>>(a);
    k_conv1<<<NBATCH, 256, 0, stream>>>(a);     // -> bufA(p1), ab1; cnt[0]
    k_bin<8,449,12,12,2,5, 4,2,111,1, 14, 8, 256><<<dim3(NBATCH,8), 64, 0, stream>>>(
        a.bufA, a.wmb + 0, a.wsc + 8, ab1, a.G[1], a.Bt[1],
        a.bufB, a.slotB2, ab2, a.holeA, a.cnt + 1);
    k_bin<12,111,32,9,1,4, 5,2,54,1, 14, 4, 128><<<dim3(NBATCH,4), 64, 0, stream>>>(
        a.bufB, a.wmb + 144, a.wsc + 20, ab2, a.G[2], a.Bt[2],
        a.bufA, a.holeA, ab3, a.holeA, a.cnt + 2);
    k_bin<32,54,64,7,1,3, 4,2,26,1, 13, 2, 64><<<dim3(NBATCH,2), 64, 0, stream>>>(
        a.bufA, a.wmb + 432, a.wsc + 52, ab3, a.G[3], a.Bt[3],
        a.bufB, a.holeA, ab4, a.holeA, a.cnt + 3);
    k_bin<64,26,64,5,1,2, 2,2,13,2, 7, 2, 64><<<dim3(NBATCH,2), 64, 0, stream>>>(
        a.bufB, a.wmb + 880, a.wsc + 116, ab4, a.G[4], a.Bt[4],
        a.bufA, a.holeA, ab5, a.holeA, a.cnt + 4);
    k_bin<64,13,64,3,1,1, 2,2,6,2, 6, 1, 64><<<dim3(NBATCH,1), 64, 0, stream>>>(
        a.bufA, a.wmb + 1520, a.wsc + 180, ab5, a.G[5], a.Bt[5],
        a.bufB, a.holeA, ab6, a.holeA, a.cnt + 5);
    k_bin<64,6,72,3,1,1, 2,2,3,2, 3, 1, 64><<<dim3(NBATCH,1), 64, 0, stream>>>(
        a.bufB, a.wmb + 1904, a.wsc + 244, ab6, a.G[6], a.Bt[6],
        a.bufA, a.holeA, ab7, a.holeA, a.cnt + 6);
    k_fc<<<NBATCH, 64, 0, stream>>>(a);
}

// Round 9
// 306.175 us; speedup vs baseline: 5.0633x; 5.0633x over previous
//
#include <hip/hip_runtime.h>
#include <math.h>
#include <stdint.h>

#define NBATCH 2048
#define NSLOT 32

struct Args {
    const float* x;
    const float* W[7];
    const float* G[7];
    const float* Bt[7];
    const float* WFC;
    float* out;
    float* bufA;      // 29,425,664 B
    float* bufB;      // 13,631,488 B
    double* stats;    // 20224 doubles
    float* wsc;       // 321 floats
    uint32_t* wmb;    // 2336 words (lives in d_out, dead until fc)
};

__device__ __forceinline__ float signf(float v) {
    return (v > 0.f) ? 1.f : ((v < 0.f) ? -1.f : 0.f);
}

// ---------------- setup: zero stats, weight scales, weight bit-pack ---------
// Weight bit layout is PERMUTED to match the float4 ballot pack:
//   CIN=64: bit 16*(c&3)+(c>>2); CIN=32: bit 8*(c&3)+(c>>2); CIN<=12: bit c.
__global__ __launch_bounds__(256) void k_setup(Args a) {
    const int blk = blockIdx.x, tid = threadIdx.x;
    for (int i = blk * 256 + tid; i < NSLOT * 632; i += 391 * 256) a.stats[i] = 0.0;

    if (blk < 321 && tid < 64) {   // mean|w| per output channel
        const int cum[9] = {0,8,20,52,116,180,244,316,321};
        const int per[8] = {16,96,108,224,320,192,192,216};
        const float* wsrc[8] = {a.W[0],a.W[1],a.W[2],a.W[3],a.W[4],a.W[5],a.W[6],a.WFC};
        int o = blk, L = 0;
        while (L < 7 && o >= cum[L + 1]) ++L;
        const int oo = o - cum[L], p = per[L];
        const float* wo = wsrc[L] + (size_t)oo * p;
        float s = 0.f;
        for (int i = tid; i < p; i += 64) s += fabsf(wo[i]);
        #pragma unroll
        for (int off = 32; off; off >>= 1) s += __shfl_down(s, off);
        if (tid == 0) a.wsc[o] = s / (float)p;
    }

    const int gid = (blk - 384) * 256 + tid;   // blocks 384..390: pack signs
    if (blk >= 384 && gid >= 0 && gid < 1608) {
        const int cum[7]  = {0,144,432,880,1200,1392,1608};
        const int cin[6]  = {8,12,32,64,64,64};
        const int kk[6]   = {12,9,7,5,3,3};
        const int wpp[6]  = {1,1,1,2,2,2};
        const int woff[6] = {0,144,432,880,1520,1904};
        const float* wsrc[6] = {a.W[1],a.W[2],a.W[3],a.W[4],a.W[5],a.W[6]};
        int L = 0;
        while (L < 5 && gid >= cum[L + 1]) ++L;
        const int idx = gid - cum[L];
        const int K = kk[L], CIN = cin[L], WPP = wpp[L];
        const int o = idx / K, k = idx - o * K;
        const float* w = wsrc[L];
        uint32_t m0 = 0, m1 = 0;
        for (int c = 0; c < CIN; ++c) {
            const float v = w[((size_t)o * CIN + c) * K + k];
            const uint32_t bit = (v < 0.f) ? 1u : 0u;
            int bp = c;
            if (CIN == 64) bp = 16 * (c & 3) + (c >> 2);
            else if (CIN == 32) bp = 8 * (c & 3) + (c >> 2);
            if (bp < 32) m0 |= bit << bp; else m1 |= bit << (bp - 32);
        }
        uint32_t* dst = a.wmb + woff[L] + (size_t)idx * WPP;
        dst[0] = m0;
        if (WPP == 2) dst[1] = m1;
    }
}

// ---------------- layer 1: register-resident conv, K=16, stride 2 -----------
__global__ __launch_bounds__(256) void k_conv1(Args a) {
    __shared__ float wgs[128];
    __shared__ double sred[16];
    const int n = blockIdx.x, tid = threadIdx.x, l = tid & 63;
    if (tid < 128) wgs[tid] = signf(a.W[0][tid]);
    if (tid < 16)  sred[tid] = 0.0;
    __syncthreads();
    const int r = tid;
    const float* xn = a.x + (size_t)n * 3600;
    float m0[8], m1[8];
    #pragma unroll
    for (int ch = 0; ch < 8; ++ch) { m0[ch] = 0.f; m1[ch] = 0.f; }
    if (r < 225) {
        float f[40];   // f[i] = x[16r-8+i]; taps f[2j+1+k] for p=8r+j
        const int g0 = 16 * r - 8;
        #pragma unroll
        for (int b = 0; b < 10; ++b) {
            const int gg = g0 + 4 * b;
            if (gg >= 0 && gg <= 3596) {
                const float4 v = *(const float4*)(xn + gg);
                f[4*b] = v.x; f[4*b+1] = v.y; f[4*b+2] = v.z; f[4*b+3] = v.w;
            } else {
                f[4*b] = 0.f; f[4*b+1] = 0.f; f[4*b+2] = 0.f; f[4*b+3] = 0.f;
            }
        }
        #pragma unroll
        for (int ch = 0; ch < 8; ++ch) {
            float acc[12];
            #pragma unroll
            for (int j = 0; j < 12; ++j) acc[j] = 0.f;
            #pragma unroll
            for (int k = 0; k < 16; ++k) {
                const float wk = wgs[ch * 16 + k];
                #pragma unroll
                for (int j = 0; j < 12; ++j)
                    acc[j] = fmaf(f[2*j + 1 + k], wk, acc[j]);
            }
            const float lo  = fmaxf(fmaxf(acc[0], acc[1]), fmaxf(acc[2], acc[3]));
            const float mid = fmaxf(fmaxf(acc[4], acc[5]), fmaxf(acc[6], acc[7]));
            const float hi  = fmaxf(fmaxf(acc[8], acc[9]), fmaxf(acc[10], acc[11]));
            const float sc = a.wsc[ch];
            m0[ch] = fmaxf(lo, mid) * sc;
            m1[ch] = (r < 224) ? fmaxf(mid, hi) * sc : 0.f;
        }
        float* on = a.bufA + ((size_t)n * 449 + 2 * r) * 8;
        *(float4*)(on + 0) = make_float4(m0[0], m0[1], m0[2], m0[3]);
        *(float4*)(on + 4) = make_float4(m0[4], m0[5], m0[6], m0[7]);
        if (r < 224) {
            *(float4*)(on + 8)  = make_float4(m1[0], m1[1], m1[2], m1[3]);
            *(float4*)(on + 12) = make_float4(m1[4], m1[5], m1[6], m1[7]);
        }
    }
    #pragma unroll
    for (int ch = 0; ch < 8; ++ch) {
        double sS = (double)m0[ch] + (double)m1[ch];
        double s2 = (double)m0[ch] * m0[ch] + (double)m1[ch] * m1[ch];
        #pragma unroll
        for (int off = 32; off; off >>= 1) {
            sS += __shfl_down(sS, off);
            s2 += __shfl_down(s2, off);
        }
        if (l == 0) {
            atomicAdd(&sred[ch], sS);
            atomicAdd(&sred[8 + ch], s2);
        }
    }
    __syncthreads();
    if (tid < 16) {
        double* so = a.stats + (size_t)(n & (NSLOT - 1)) * 16;
        atomicAdd(&so[tid], sred[tid]);
    }
}

// ---------------- layers 2..7: wave-per-(sample, lp-slice) binary conv ------
// Pack phase uses float4 loads (4 channels/lane, 4 ballots -> 4x positions
// per load issue) to shorten the per-wave latency chain.
template <int CIN, int LIN, int O, int K, int STRIDE, int PAD,
          int PK, int PS, int LP, int WPP, int LPB>
__global__ __launch_bounds__(64) void k_bin(
    const float* __restrict__ xprev, const uint32_t* __restrict__ wm,
    const float* __restrict__ wsc, const double* __restrict__ stats_in,
    const float* __restrict__ gamma, const float* __restrict__ beta,
    const double cntInv, float* __restrict__ out, double* __restrict__ stats_out)
{
    constexpr int OL    = (O < 64) ? O : 64;
    constexpr int PO    = 64 / OL;
    constexpr int SPAN  = (PK - 1) * STRIDE + K;
    constexpr int SHIFT = (WPP == 1) ? (PAD & 1) : 0;
    constexpr int XMN   = LPB * PS * STRIDE + SPAN + 2;
    constexpr int XM64N = (WPP == 2) ? XMN : ((XMN + 2) / 2 + 1);

    __shared__ uint64_t xmbuf[XM64N];
    uint32_t* xm32 = (uint32_t*)xmbuf;
    uint64_t* xm64 = xmbuf;

    const int n = blockIdx.x, sp = blockIdx.y, l = threadIdx.x;
    const int lp0 = sp * LPB;
    const int lp1 = (lp0 + LPB < LP) ? lp0 + LPB : LP;
    const int q0raw = lp0 * PS * STRIDE - PAD;
    const int q0 = (q0raw > 0) ? q0raw : 0;
    const int q1raw = (lp1 - 1) * PS * STRIDE - PAD + SPAN;
    const int q1 = (q1raw < LIN) ? q1raw : LIN;
    const int S0 = (WPP == 1) ? ((q0 + SHIFT) & 1) : 0;
    const int xbase = q0 - S0;

    const float* xn = xprev + (size_t)n * LIN * CIN;

    // BN fold of previous layer's stats (lane c = l), broadcast via shfl
    float aA = 0.f, aB = 0.f;
    if (l < CIN) {
        double s = 0.0, s2 = 0.0;
        #pragma unroll 8
        for (int sl = 0; sl < NSLOT; ++sl) {
            s  += stats_in[sl * 2 * CIN + l];
            s2 += stats_in[sl * 2 * CIN + CIN + l];
        }
        const double mean = s * cntInv;
        const double var  = s2 * cntInv - mean * mean;
        const double inv  = 1.0 / sqrt(var + 1e-5);
        const double av   = (double)gamma[l] * inv;
        aA = (float)av;
        aB = (float)((double)beta[l] - mean * av);
    }

    // ---- pack slice [q0, q1) ----
    if constexpr (CIN == 64) {
        const int sub = l & 15, grp = l >> 4;       // ch base 4*sub, pos += grp
        const float a0 = __shfl(aA, 4*sub),     b0 = __shfl(aB, 4*sub);
        const float a1 = __shfl(aA, 4*sub + 1), b1 = __shfl(aB, 4*sub + 1);
        const float a2 = __shfl(aA, 4*sub + 2), b2 = __shfl(aB, 4*sub + 2);
        const float a3 = __shfl(aA, 4*sub + 3), b3 = __shfl(aB, 4*sub + 3);
        for (int pb = q0; pb < q1; pb += 4) {
            const int pos = pb + grp;
            const bool valid = pos < q1;
            const float4 v = *(const float4*)(xn + (size_t)(valid ? pos : q0) * 64 + 4*sub);
            const unsigned long long bal0 = __ballot(valid && (fmaf(a0, v.x, b0) < 0.f));
            const unsigned long long bal1 = __ballot(valid && (fmaf(a1, v.y, b1) < 0.f));
            const unsigned long long bal2 = __ballot(valid && (fmaf(a2, v.z, b2) < 0.f));
            const unsigned long long bal3 = __ballot(valid && (fmaf(a3, v.w, b3) < 0.f));
            if (l < 4 && pb + l < q1) {
                const uint64_t m = ((bal0 >> (16*l)) & 0xFFFFull)
                                 | (((bal1 >> (16*l)) & 0xFFFFull) << 16)
                                 | (((bal2 >> (16*l)) & 0xFFFFull) << 32)
                                 | (((bal3 >> (16*l)) & 0xFFFFull) << 48);
                xm64[pb + l - xbase] = m;
            }
        }
    } else if constexpr (CIN == 32) {
        const int sub = l & 7, grp = l >> 3;        // ch base 4*sub, pos += grp
        const float a0 = __shfl(aA, 4*sub),     b0 = __shfl(aB, 4*sub);
        const float a1 = __shfl(aA, 4*sub + 1), b1 = __shfl(aB, 4*sub + 1);
        const float a2 = __shfl(aA, 4*sub + 2), b2 = __shfl(aB, 4*sub + 2);
        const float a3 = __shfl(aA, 4*sub + 3), b3 = __shfl(aB, 4*sub + 3);
        for (int pb = q0; pb < q1; pb += 8) {
            const int pos = pb + grp;
            const bool valid = pos < q1;
            const float4 v = *(const float4*)(xn + (size_t)(valid ? pos : q0) * 32 + 4*sub);
            const unsigned long long bal0 = __ballot(valid && (fmaf(a0, v.x, b0) < 0.f));
            const unsigned long long bal1 = __ballot(valid && (fmaf(a1, v.y, b1) < 0.f));
            const unsigned long long bal2 = __ballot(valid && (fmaf(a2, v.z, b2) < 0.f));
            const unsigned long long bal3 = __ballot(valid && (fmaf(a3, v.w, b3) < 0.f));
            if (l < 8 && pb + l < q1) {
                const uint32_t m = (uint32_t)((bal0 >> (8*l)) & 0xFFull)
                                 | ((uint32_t)((bal1 >> (8*l)) & 0xFFull) << 8)
                                 | ((uint32_t)((bal2 >> (8*l)) & 0xFFull) << 16)
                                 | ((uint32_t)((bal3 >> (8*l)) & 0xFFull) << 24);
                xm32[pb + l - xbase] = m;
            }
        }
    } else if constexpr (CIN == 8) {
        const int sub = l & 1, grp = l >> 1;        // ch base 4*sub, pos += grp
        const float a0 = __shfl(aA, 4*sub),     b0 = __shfl(aB, 4*sub);
        const float a1 = __shfl(aA, 4*sub + 1), b1 = __shfl(aB, 4*sub + 1);
        const float a2 = __shfl(aA, 4*sub + 2), b2 = __shfl(aB, 4*sub + 2);
        const float a3 = __shfl(aA, 4*sub + 3), b3 = __shfl(aB, 4*sub + 3);
        for (int pb = q0; pb < q1; pb += 32) {
            const int pos = pb + grp;
            const bool valid = pos < q1;
            const float4 v = *(const float4*)(xn + (size_t)(valid ? pos : q0) * 8 + 4*sub);
            const unsigned long long bal0 = __ballot(valid && (fmaf(a0, v.x, b0) < 0.f));
            const unsigned long long bal1 = __ballot(valid && (fmaf(a1, v.y, b1) < 0.f));
            const unsigned long long bal2 = __ballot(valid && (fmaf(a2, v.z, b2) < 0.f));
            const unsigned long long bal3 = __ballot(valid && (fmaf(a3, v.w, b3) < 0.f));
            if (l < 32 && pb + l < q1) {
                const uint32_t t0 = (uint32_t)((bal0 >> (2*l)) & 3ull);
                const uint32_t t1 = (uint32_t)((bal1 >> (2*l)) & 3ull);
                const uint32_t t2 = (uint32_t)((bal2 >> (2*l)) & 3ull);
                const uint32_t t3 = (uint32_t)((bal3 >> (2*l)) & 3ull);
                const uint32_t m = (t0 & 1) | ((t1 & 1) << 1) | ((t2 & 1) << 2) | ((t3 & 1) << 3)
                                 | ((t0 >> 1) << 4) | ((t1 >> 1) << 5) | ((t2 >> 1) << 6) | ((t3 >> 1) << 7);
                xm32[pb + l - xbase] = m;
            }
        }
    } else {   // CIN == 12 generic ballot path
        constexpr int PPW = 64 / CIN;
        const int pw = l / CIN, c = l - pw * CIN;
        const float myA = __shfl(aA, c), myB = __shfl(aB, c);
        const bool lact = (pw < PPW);
        for (int pb = q0; pb < q1; pb += PPW) {
            const int pos = pb + pw;
            const bool act = lact && (pos < q1);
            float v = 0.f;
            if (act) v = fmaf(myA, xn[(size_t)pb * CIN + l], myB);
            const unsigned long long bal = __ballot(act && (v < 0.f));
            if (act && c == 0) {
                const uint32_t mk = (uint32_t)((bal >> (pw * CIN)) & ((1u << CIN) - 1));
                xm32[pos - xbase] = mk;
            }
        }
    }
    __syncthreads();

    // ---- conv + pool + stats over [lp0, lp1) ----
    const int po = l / OL, oo = l - po * OL;
    const bool cact = (po < PO);
    const float myws = cact ? wsc[oo] : 0.f;
    float* on = out + (size_t)n * LP * O;
    double accS = 0.0, accS2 = 0.0;
    double* so = stats_out + (size_t)(n & (NSLOT - 1)) * 2 * O;

    if constexpr (WPP == 2) {
        const uint64_t* wmp = (const uint64_t*)wm;
        uint64_t wr[K];
        #pragma unroll
        for (int k = 0; k < K; ++k) wr[k] = wmp[oo * K + k];
        uint64_t wr2[K];
        const int oo2 = 64 + ((O > 64 && l < O - 64) ? l : 0);
        if constexpr (O > 64) {
            #pragma unroll
            for (int k = 0; k < K; ++k) wr2[k] = wmp[oo2 * K + k];
        }
        const float myws2 = (O > 64 && l < O - 64) ? wsc[64 + l] : 0.f;
        double accSb = 0.0, accS2b = 0.0;

        for (int lp = lp0 + po; lp < lp1; lp += PO) {
            const int lo = lp * PS * STRIDE - PAD;
            int m = -1000000, m2 = -1000000;
            if (lo >= 0 && lo + SPAN <= LIN) {
                uint64_t tw[SPAN];
                #pragma unroll
                for (int t = 0; t < SPAN; ++t) tw[t] = xm64[lo - xbase + t];
                #pragma unroll
                for (int j = 0; j < PK; ++j) {
                    int p = 0;
                    #pragma unroll
                    for (int k = 0; k < K; ++k)
                        p += __popcll(tw[j * STRIDE + k] ^ wr[k]);
                    m = max(m, CIN * K - 2 * p);
                    if constexpr (O > 64) {
                        int p2 = 0;
                        #pragma unroll
                        for (int k = 0; k < K; ++k)
                            p2 += __popcll(tw[j * STRIDE + k] ^ wr2[k]);
                        m2 = max(m2, CIN * K - 2 * p2);
                    }
                }
            } else {
                #pragma unroll
                for (int j = 0; j < PK; ++j) {
                    const int base = lo + j * STRIDE;
                    int p = 0, nv = 0, p2 = 0;
                    #pragma unroll
                    for (int k = 0; k < K; ++k) {
                        const int q = base + k;
                        if (q >= 0 && q < LIN) {
                            ++nv;
                            const uint64_t xv = xm64[q - xbase];
                            p += __popcll(xv ^ wr[k]);
                            if constexpr (O > 64) p2 += __popcll(xv ^ wr2[k]);
                        }
                    }
                    m = max(m, CIN * nv - 2 * p);
                    if constexpr (O > 64) m2 = max(m2, CIN * nv - 2 * p2);
                }
            }
            const float mv = (float)m * myws;
            on[lp * O + oo] = mv;
            accS += mv; accS2 += (double)mv * mv;
            if constexpr (O > 64) {
                const float mv2 = (float)m2 * myws2;
                if (l < O - 64) on[lp * O + 64 + l] = mv2;
                accSb += mv2; accS2b += (double)mv2 * mv2;
            }
        }
        atomicAdd(&so[oo], accS);
        atomicAdd(&so[O + oo], accS2);
        if constexpr (O > 64) {
            if (l < O - 64) {
                atomicAdd(&so[64 + l], accSb);
                atomicAdd(&so[O + 64 + l], accS2b);
            }
        }
    } else {
        uint32_t wr[K];
        #pragma unroll
        for (int k = 0; k < K; ++k) wr[k] = wm[oo * K + k];

        constexpr int PAIRS = (SPAN + 1) / 2;
        for (int lp = lp0 + po; lp < lp1; lp += PO) {
            const int lo = lp * PS * STRIDE - PAD;   // (lo+SHIFT) even
            int m = -1000000;
            if (lo >= 0 && lo + SPAN <= LIN) {
                uint32_t tw[PAIRS * 2];
                const int e0 = (lo - xbase) >> 1;    // (lo-xbase) even
                #pragma unroll
                for (int i = 0; i < PAIRS; ++i) {
                    const uint64_t u = xmbuf[e0 + i];
                    tw[2 * i]     = (uint32_t)u;
                    tw[2 * i + 1] = (uint32_t)(u >> 32);
                }
                #pragma unroll
                for (int j = 0; j < PK; ++j) {
                    int p = 0;
                    #pragma unroll
                    for (int k = 0; k < K; ++k)
                        p += __popc(tw[j * STRIDE + k] ^ wr[k]);
                    m = max(m, CIN * K - 2 * p);
                }
            } else {
                #pragma unroll
                for (int j = 0; j < PK; ++j) {
                    const int base = lo + j * STRIDE;
                    int p = 0, nv = 0;
                    #pragma unroll
                    for (int k = 0; k < K; ++k) {
                        const int q = base + k;
                        if (q >= 0 && q < LIN) { ++nv; p += __popc(xm32[q - xbase] ^ wr[k]); }
                    }
                    m = max(m, CIN * nv - 2 * p);
                }
            }
            const float mv = (float)m * myws;
            if (cact) on[lp * O + oo] = mv;
            accS += mv; accS2 += (double)mv * mv;
        }
        if constexpr (PO > 1) {
            double t = accS, t2 = accS2;
            #pragma unroll
            for (int g = 1; g < PO; ++g) {
                t  += __shfl(accS,  l + g * OL);
                t2 += __shfl(accS2, l + g * OL);
            }
            if (l < OL) { atomicAdd(&so[l], t); atomicAdd(&so[O + l], t2); }
        } else {
            atomicAdd(&so[oo], accS);
            atomicAdd(&so[O + oo], accS2);
        }
    }
}

// ---------------- FC, wave-per-sample (computes L7 BN fold inline) ----------
__global__ __launch_bounds__(64) void k_fc(Args a) {
    const int n = blockIdx.x, l = threadIdx.x;
    const double* st = a.stats + 15616;
    double s = 0.0, s2 = 0.0, sb = 0.0, s2b = 0.0;
    #pragma unroll 4
    for (int sl = 0; sl < NSLOT; ++sl) {
        s  += st[sl * 144 + l];
        s2 += st[sl * 144 + 72 + l];
        if (l < 8) {
            sb  += st[sl * 144 + 64 + l];
            s2b += st[sl * 144 + 72 + 64 + l];
        }
    }
    float aA0, aB0, aA1 = 0.f, aB1 = 0.f;
    {
        const double mean = s / 6144.0, var = s2 / 6144.0 - mean * mean;
        const double inv = 1.0 / sqrt(var + 1e-5);
        const double aa = (double)a.G[6][l] * inv;
        aA0 = (float)aa; aB0 = (float)((double)a.Bt[6][l] - mean * aa);
    }
    if (l < 8) {
        const double mean = sb / 6144.0, var = s2b / 6144.0 - mean * mean;
        const double inv = 1.0 / sqrt(var + 1e-5);
        const double aa = (double)a.G[6][64 + l] * inv;
        aA1 = (float)aa; aB1 = (float)((double)a.Bt[6][64 + l] - mean * aa);
    }
    const float* p7 = a.bufA + (size_t)n * 216;
    float acc[5] = {0.f, 0.f, 0.f, 0.f, 0.f};
    #pragma unroll
    for (int j = 0; j < 4; ++j) {
        const int i = l + 64 * j;
        const int ic = (i < 216) ? i : 215;
        const int c = ic / 3, lp = ic - 3 * c;       // flatten is [72,3]
        float aa = __shfl(aA0, c);
        float bb = __shfl(aB0, c);
        const float aaH = __shfl(aA1, c - 64);
        const float bbH = __shfl(aB1, c - 64);
        if (c >= 64) { aa = aaH; bb = bbH; }
        if (i < 216) {
            const float av = signf(fmaf(aa, p7[lp * 72 + c], bb));
            #pragma unroll
            for (int o = 0; o < 5; ++o)
                acc[o] += av * signf(a.WFC[o * 216 + i]);
        }
    }
    #pragma unroll
    for (int o = 0; o < 5; ++o) {
        float v = acc[o];
        #pragma unroll
        for (int off = 32; off; off >>= 1) v += __shfl_down(v, off);
        if (l == 0) a.out[(size_t)n * 5 + o] = v * a.wsc[316 + o];
    }
}

extern "C" void kernel_launch(void* const* d_in, const int* in_sizes, int n_in,
                              void* d_out, int out_size, void* d_ws, size_t ws_size,
                              hipStream_t stream) {
    Args a;
    a.x = (const float*)d_in[0];
    for (int i = 0; i < 7; ++i) {
        a.W[i]  = (const float*)d_in[1 + 3 * i];
        a.G[i]  = (const float*)d_in[2 + 3 * i];
        a.Bt[i] = (const float*)d_in[3 + 3 * i];
    }
    a.WFC = (const float*)d_in[22];
    a.out = (float*)d_out;

    char* ws = (char*)d_ws;
    a.bufA  = (float*)ws;                       // 29,425,664 B
    a.bufB  = (float*)(ws + 29425664);          // 13,631,488 B
    a.stats = (double*)(ws + 43057152);         // 20224 doubles
    a.wsc   = (float*)(ws + 43218944);          // 1284 B
    a.wmb   = (uint32_t*)d_out;                 // 9344 B, dead before fc writes

    k_setup<<<391, 256, 0, stream>>>(a);
    k_conv1<<<NBATCH, 256, 0, stream>>>(a);
    // stats (doubles): L1@0, L2@512, L3@1280, L4@3328, L5@7424, L6@11520, L7@15616
    k_bin<8,449,12,12,2,5,4,2,111,1,14><<<dim3(NBATCH,8), 64, 0, stream>>>(
        a.bufA, a.wmb + 0, a.wsc + 8, a.stats + 0, a.G[0], a.Bt[0],
        1.0/919552.0, a.bufB, a.stats + 512);
    k_bin<12,111,32,9,1,4,5,2,54,1,14><<<dim3(NBATCH,4), 64, 0, stream>>>(
        a.bufB, a.wmb + 144, a.wsc + 20, a.stats + 512, a.G[1], a.Bt[1],
        1.0/227328.0, a.bufA, a.stats + 1280);
    k_bin<32,54,64,7,1,3,4,2,26,1,13><<<dim3(NBATCH,2), 64, 0, stream>>>(
        a.bufA, a.wmb + 432, a.wsc + 52, a.stats + 1280, a.G[2], a.Bt[2],
        1.0/110592.0, a.bufB, a.stats + 3328);
    k_bin<64,26,64,5,1,2,2,2,13,2,7><<<dim3(NBATCH,2), 64, 0, stream>>>(
        a.bufB, a.wmb + 880, a.wsc + 116, a.stats + 3328, a.G[3], a.Bt[3],
        1.0/53248.0, a.bufA, a.stats + 7424);
    k_bin<64,13,64,3,1,1,2,2,6,2,6><<<dim3(NBATCH,1), 64, 0, stream>>>(
        a.bufA, a.wmb + 1520, a.wsc + 180, a.stats + 7424, a.G[4], a.Bt[4],
        1.0/26624.0, a.bufB, a.stats + 11520);
    k_bin<64,6,72,3,1,1,2,2,3,2,3><<<dim3(NBATCH,1), 64, 0, stream>>>(
        a.bufB, a.wmb + 1904, a.wsc + 244, a.stats + 11520, a.G[5], a.Bt[5],
        1.0/12288.0, a.bufA, a.stats + 15616);
    k_fc<<<NBATCH, 64, 0, stream>>>(a);
}